// Round 6
// baseline (148.411 us; speedup 1.0000x reference)
//
#include <hip/hip_runtime.h>
#include <math.h>

#define MARGIN 0.3f
#define BIGF 1e9f
#define NN 512
#define DD 2048
#define LDIM 128
#define PARTS 8

typedef __attribute__((ext_vector_type(8))) __bf16 bf16x8;
typedef __attribute__((ext_vector_type(4))) float f32x4;

// ---------------------------------------------------------------------------
// Fused: [phase 1] G = X X^T (single-bf16 MFMA, 64x64 tiles, split-K=8,
//                  double-buffered LDS) — identical math to round-5 k_gram.
//        [barrier] device-wide: release fence (1 wbl2/block) + RELAXED spin
//                  (global_load sc0 sc1, NO per-poll cache maintenance) +
//                  ONE acquire (1 inv/block). Co-residency: grid 512 =
//                  2 blocks/CU exactly, launch_bounds(256,2), 48KB LDS*2<=160.
//        [phase 2] hard mining + local DTW + ticket finalize — identical to
//                  round-5 k_mine_local.
// ---------------------------------------------------------------------------
__global__ __launch_bounds__(256, 2) void k_fused(
    const float* __restrict__ X, const int* __restrict__ tg,
    const float* __restrict__ LF, float* __restrict__ Gp,
    float* __restrict__ ndiag, float* gsum, float* lsum,
    unsigned* ticket, unsigned* bar, float* __restrict__ out)
{
    __shared__ __bf16 A[2][4096], B[2][4096];   // 32 KB (phase 1)
    __shared__ float sdiag[NN];                  // phase 2 arrays (~15 KB)
    __shared__ float s_apv[4]; __shared__ int s_api[4];
    __shared__ float s_anv[4]; __shared__ int s_ani[4];
    __shared__ int sh_pn[2];
    __shared__ float A2[LDIM * PARTS];
    __shared__ float B2[2][LDIM * PARTS];
    __shared__ float dtm[2][64];
    __shared__ float res[2];

    int bid = blockIdx.x;
    int tj = bid & 7, ti = (bid >> 3) & 7, ks = bid >> 6;
    int t = threadIdx.x;
    int w = t >> 6, lane = t & 63;
    int wr = w >> 1, wc = w & 1;

    // ---------------- phase 1: gram tile ----------------
    int m = t >> 7;
    int r = (t >> 1) & 63;
    int kst = t & 1;
    int grow = (m ? tj : ti) * 64 + r;
    const float4* gp4 = (const float4*)(X + (size_t)grow * DD + ks * 256 + kst * 32);
    int ebase = kst * 2048 + (r >> 4) * 512 + (r & 15) * 8;

    float4 cur[8];
#pragma unroll
    for (int q = 0; q < 8; q++) cur[q] = gp4[q];

    f32x4 acc00 = {0.f, 0.f, 0.f, 0.f};
    f32x4 acc01 = {0.f, 0.f, 0.f, 0.f};
    f32x4 acc10 = {0.f, 0.f, 0.f, 0.f};
    f32x4 acc11 = {0.f, 0.f, 0.f, 0.f};

    {
        __bf16* hb = (m ? B[0] : A[0]) + ebase;
#pragma unroll
        for (int jg = 0; jg < 4; jg++) {
            float fe[8] = {cur[2 * jg].x, cur[2 * jg].y, cur[2 * jg].z, cur[2 * jg].w,
                           cur[2 * jg + 1].x, cur[2 * jg + 1].y, cur[2 * jg + 1].z, cur[2 * jg + 1].w};
            bf16x8 h;
#pragma unroll
            for (int e = 0; e < 8; e++) h[e] = (__bf16)fe[e];
            *(bf16x8*)(hb + jg * 128) = h;
        }
    }

#pragma unroll
    for (int it = 0; it < 4; ++it) {
        __syncthreads();
        if (it < 3) {
            const float4* np = gp4 + (it + 1) * 16;
#pragma unroll
            for (int q = 0; q < 8; q++) cur[q] = np[q];
        }
        int buf = it & 1;
#pragma unroll
        for (int kstep = 0; kstep < 2; kstep++) {
            const bf16x8* fA = (const bf16x8*)&A[buf][kstep * 2048 + wr * 1024];
            const bf16x8* fB = (const bf16x8*)&B[buf][kstep * 2048 + wc * 1024];
            bf16x8 ah0 = fA[lane], ah1 = fA[lane + 64];
            bf16x8 bh0 = fB[lane], bh1 = fB[lane + 64];
            acc00 = __builtin_amdgcn_mfma_f32_16x16x32_bf16(ah0, bh0, acc00, 0, 0, 0);
            acc01 = __builtin_amdgcn_mfma_f32_16x16x32_bf16(ah0, bh1, acc01, 0, 0, 0);
            acc10 = __builtin_amdgcn_mfma_f32_16x16x32_bf16(ah1, bh0, acc10, 0, 0, 0);
            acc11 = __builtin_amdgcn_mfma_f32_16x16x32_bf16(ah1, bh1, acc11, 0, 0, 0);
        }
        if (it < 3) {
            int nb = (it + 1) & 1;
            __bf16* hb = (m ? B[nb] : A[nb]) + ebase;
#pragma unroll
            for (int jg = 0; jg < 4; jg++) {
                float fe[8] = {cur[2 * jg].x, cur[2 * jg].y, cur[2 * jg].z, cur[2 * jg].w,
                               cur[2 * jg + 1].x, cur[2 * jg + 1].y, cur[2 * jg + 1].z, cur[2 * jg + 1].w};
                bf16x8 h;
#pragma unroll
                for (int e = 0; e < 8; e++) h[e] = (__bf16)fe[e];
                *(bf16x8*)(hb + jg * 128) = h;
            }
        }
    }

    // epilogue: C/D layout col = lane&15, row = (lane>>4)*4 + reg
    int rbase = ti * 64 + wr * 32 + ((lane >> 4) << 2);
    int cbase = tj * 64 + wc * 32 + (lane & 15);
    float* gb = Gp + (size_t)ks * NN * NN;
    f32x4 accs[2][2] = {{acc00, acc01}, {acc10, acc11}};
#pragma unroll
    for (int g = 0; g < 2; g++)
#pragma unroll
        for (int h = 0; h < 2; h++)
#pragma unroll
            for (int rr = 0; rr < 4; rr++)
                gb[(size_t)(rbase + g * 16 + rr) * NN + cbase + h * 16] = accs[g][h][rr];

    if (ti == tj && wr == wc && ((lane >> 4) == ((lane & 15) >> 2))) {
        int rr = lane & 3;
        int row0 = rbase + rr;
        ndiag[ks * NN + row0]      = acc00[rr];
        ndiag[ks * NN + row0 + 16] = acc11[rr];
    }

    // ---------------- device-wide barrier (relaxed spin) ----------------
    __syncthreads();                        // all waves' stores issued
    if (t == 0) {
        __threadfence();                    // release: drain + L2 writeback (once/block)
        __hip_atomic_fetch_add(bar, 1u, __ATOMIC_RELAXED, __HIP_MEMORY_SCOPE_AGENT);
        // RELAXED poll: global_load sc0 sc1 (coherent-point read), no inv
        while (__hip_atomic_load(bar, __ATOMIC_RELAXED, __HIP_MEMORY_SCOPE_AGENT)
               < (unsigned)NN)
            __builtin_amdgcn_s_sleep(8);
        // single acquire: one L1/L2 invalidate per block
        (void)__hip_atomic_load(bar, __ATOMIC_ACQUIRE, __HIP_MEMORY_SCOPE_AGENT);
    }
    __syncthreads();                        // all waves wait; loads below are fresh

    // ---------------- phase 2: mining + local DTW ----------------
    int i = bid;

    float d0 = 0.f, d1 = 0.f;
#pragma unroll
    for (int kk = 0; kk < 8; kk++) {
        d0 += ndiag[kk * NN + t];
        d1 += ndiag[kk * NN + t + 256];
    }
    sdiag[t] = d0;
    sdiag[t + 256] = d1;
    __syncthreads();

    float ni = sdiag[i];
    int tgt_i = tg[i];

    float apv = -BIGF; int api = 0x7fffffff;
    float anv =  BIGF; int ani = 0x7fffffff;

#pragma unroll
    for (int jj = 0; jj < 2; jj++) {
        int j = t + jj * 256;
        float g = 0.f;
#pragma unroll
        for (int kk = 0; kk < 8; kk++)
            g += Gp[(size_t)kk * NN * NN + (size_t)i * NN + j];
        float nj = (jj == 0) ? d0 : d1;
        float dd = ni + nj - 2.0f * g;
        float dist = sqrtf(fmaxf(dd, 1e-12f));
        bool pos = (tg[j] == tgt_i);
        float a = pos ? dist : -BIGF;
        if (a > apv || (a == apv && j < api)) { apv = a; api = j; }
        float b = pos ? BIGF : dist;
        if (b < anv || (b == anv && j < ani)) { anv = b; ani = j; }
    }
    for (int off = 32; off > 0; off >>= 1) {
        float av = __shfl_down(apv, off); int ai = __shfl_down(api, off);
        if (av > apv || (av == apv && ai < api)) { apv = av; api = ai; }
        float nv = __shfl_down(anv, off); int nid = __shfl_down(ani, off);
        if (nv < anv || (nv == anv && nid < ani)) { anv = nv; ani = nid; }
    }
    if (lane == 0) { s_apv[w] = apv; s_api[w] = api;
                     s_anv[w] = anv; s_ani[w] = ani; }
    __syncthreads();
    if (t == 0) {
        apv = s_apv[0]; api = s_api[0]; anv = s_anv[0]; ani = s_ani[0];
        for (int wv = 1; wv < 4; wv++) {
            float av = s_apv[wv]; int ai = s_api[wv];
            if (av > apv || (av == apv && ai < api)) { apv = av; api = ai; }
            float nv = s_anv[wv]; int nid = s_ani[wv];
            if (nv < anv || (nv == anv && nid < ani)) { anv = nv; ani = nid; }
        }
        sh_pn[0] = api;
        sh_pn[1] = ani;
        atomicAdd(gsum, fmaxf(0.0f, MARGIN + apv - anv));
    }
    __syncthreads();

    ((float4*)A2)[t] = ((const float4*)(LF + (size_t)i * LDIM * PARTS))[t];
    if (w < 2) {
        int ind = sh_pn[w];
        const float4* B4 = (const float4*)(LF + (size_t)ind * LDIM * PARTS);
        float4* Bw = (float4*)B2[w];
        Bw[lane]       = B4[lane];
        Bw[lane + 64]  = B4[lane + 64];
        Bw[lane + 128] = B4[lane + 128];
        Bw[lane + 192] = B4[lane + 192];
    }
    __syncthreads();

    if (w < 2) {
        int p = lane >> 3, q = lane & 7;
        float acc = 0.0f;
        const float* Bw = B2[w];
        for (int d = 0; d < LDIM; d++) {
            float diff = A2[d * PARTS + p] - Bw[d * PARTS + q];
            acc = fmaf(diff, diff, acc);
        }
        float dist = sqrtf(fmaxf(acc, 1e-12f));
        dtm[w][p * 8 + q] = tanhf(0.5f * dist);
    }
    __syncthreads();

    if ((t == 0) || (t == 64)) {
        const float* dm = dtm[w];
        float dp[8];
        dp[0] = dm[0];
        for (int j = 1; j < 8; j++) dp[j] = dp[j - 1] + dm[j];
        for (int rr = 1; rr < 8; rr++) {
            dp[0] += dm[rr * 8];
            for (int j = 1; j < 8; j++)
                dp[j] = dm[rr * 8 + j] + fminf(dp[j], dp[j - 1]);
        }
        res[w] = dp[7];
    }
    __syncthreads();

    if (t == 0) {
        float l = fmaxf(0.0f, MARGIN + res[0] - res[1]);
        atomicAdd(lsum, l);
        __threadfence();
        unsigned old = atomicAdd(ticket, 1u);
        if (old == (NN - 1)) {
            __threadfence();
            float ls = atomicAdd(lsum, 0.0f);
            float gs = atomicAdd(gsum, 0.0f);
            out[0] = gs * (1.0f / NN);
            out[1] = ls * (1.0f / NN);
        }
    }
}

// ---------------------------------------------------------------------------
extern "C" void kernel_launch(void* const* d_in, const int* in_sizes, int n_in,
                              void* d_out, int out_size, void* d_ws, size_t ws_size,
                              hipStream_t stream)
{
    const float* X  = (const float*)d_in[0];   // [512, 2048] fp32
    const int*   tg = (const int*)d_in[1];     // [512] int
    const float* LF = (const float*)d_in[2];   // [512, 128, 8] fp32
    float* out = (float*)d_out;                // 2 fp32 scalars

    char* ws = (char*)d_ws;
    float*    Gp      = (float*)ws;                          // 8 x 1 MB partials
    float*    ndiag   = (float*)(ws + (8u << 20));           // 16 KB
    char*     ctr     = ws + (8u << 20) + 16384;             // 16 B counters
    float*    gsum    = (float*)(ctr + 0);
    float*    lsum    = (float*)(ctr + 4);
    unsigned* ticket  = (unsigned*)(ctr + 8);
    unsigned* bar     = (unsigned*)(ctr + 12);

    hipMemsetAsync(ctr, 0, 16, stream);
    k_fused<<<NN, 256, 0, stream>>>(X, tg, LF, Gp, ndiag, gsum, lsum,
                                    ticket, bar, out);
}

// Round 7
// 93.436 us; speedup vs baseline: 1.5884x; 1.5884x over previous
//
#include <hip/hip_runtime.h>
#include <math.h>

#define MARGIN 0.3f
#define BIGF 1e9f
#define NN 512
#define DD 2048
#define LDIM 128
#define PARTS 8

typedef __attribute__((ext_vector_type(8))) __bf16 bf16x8;
typedef __attribute__((ext_vector_type(4))) float f32x4;

// ---------------------------------------------------------------------------
// K1: G = X X^T via single-bf16 MFMA. 64x64 tiles, split-K=8, grid 512 =
//     2 blocks/CU. Double-buffered LDS. Partials stored as fp16 (err ~1e-3
//     on dist; threshold 7.25e-2). Norms harvested fp32 off the diagonal.
// ---------------------------------------------------------------------------
__global__ __launch_bounds__(256, 2) void k_gram(
    const float* __restrict__ X, _Float16* __restrict__ Gp,
    float* __restrict__ ndiag, float* gsum, float* lsum, unsigned* counter)
{
    __shared__ __bf16 A[2][4096], B[2][4096];   // 32 KB

    int bid = blockIdx.x;
    int tj = bid & 7, ti = (bid >> 3) & 7, ks = bid >> 6;
    int t = threadIdx.x;
    int w = t >> 6, lane = t & 63;
    int wr = w >> 1, wc = w & 1;

    if (bid == 0 && t == 0) { *gsum = 0.0f; *lsum = 0.0f; *counter = 0u; }

    int m = t >> 7;
    int r = (t >> 1) & 63;
    int kst = t & 1;
    int grow = (m ? tj : ti) * 64 + r;
    const float4* gp4 = (const float4*)(X + (size_t)grow * DD + ks * 256 + kst * 32);
    int ebase = kst * 2048 + (r >> 4) * 512 + (r & 15) * 8;

    float4 cur[8];
#pragma unroll
    for (int q = 0; q < 8; q++) cur[q] = gp4[q];

    f32x4 acc00 = {0.f, 0.f, 0.f, 0.f};
    f32x4 acc01 = {0.f, 0.f, 0.f, 0.f};
    f32x4 acc10 = {0.f, 0.f, 0.f, 0.f};
    f32x4 acc11 = {0.f, 0.f, 0.f, 0.f};

    {
        __bf16* hb = (m ? B[0] : A[0]) + ebase;
#pragma unroll
        for (int jg = 0; jg < 4; jg++) {
            float fe[8] = {cur[2 * jg].x, cur[2 * jg].y, cur[2 * jg].z, cur[2 * jg].w,
                           cur[2 * jg + 1].x, cur[2 * jg + 1].y, cur[2 * jg + 1].z, cur[2 * jg + 1].w};
            bf16x8 h;
#pragma unroll
            for (int e = 0; e < 8; e++) h[e] = (__bf16)fe[e];
            *(bf16x8*)(hb + jg * 128) = h;
        }
    }

#pragma unroll
    for (int it = 0; it < 4; ++it) {
        __syncthreads();                       // buf[it&1] staged & prior reads done
        if (it < 3) {
            const float4* np = gp4 + (it + 1) * 16;
#pragma unroll
            for (int q = 0; q < 8; q++) cur[q] = np[q];
        }
        int buf = it & 1;
#pragma unroll
        for (int kstep = 0; kstep < 2; kstep++) {
            const bf16x8* fA = (const bf16x8*)&A[buf][kstep * 2048 + wr * 1024];
            const bf16x8* fB = (const bf16x8*)&B[buf][kstep * 2048 + wc * 1024];
            bf16x8 ah0 = fA[lane], ah1 = fA[lane + 64];
            bf16x8 bh0 = fB[lane], bh1 = fB[lane + 64];
            acc00 = __builtin_amdgcn_mfma_f32_16x16x32_bf16(ah0, bh0, acc00, 0, 0, 0);
            acc01 = __builtin_amdgcn_mfma_f32_16x16x32_bf16(ah0, bh1, acc01, 0, 0, 0);
            acc10 = __builtin_amdgcn_mfma_f32_16x16x32_bf16(ah1, bh0, acc10, 0, 0, 0);
            acc11 = __builtin_amdgcn_mfma_f32_16x16x32_bf16(ah1, bh1, acc11, 0, 0, 0);
        }
        if (it < 3) {
            int nb = (it + 1) & 1;
            __bf16* hb = (m ? B[nb] : A[nb]) + ebase;
#pragma unroll
            for (int jg = 0; jg < 4; jg++) {
                float fe[8] = {cur[2 * jg].x, cur[2 * jg].y, cur[2 * jg].z, cur[2 * jg].w,
                               cur[2 * jg + 1].x, cur[2 * jg + 1].y, cur[2 * jg + 1].z, cur[2 * jg + 1].w};
                bf16x8 h;
#pragma unroll
                for (int e = 0; e < 8; e++) h[e] = (__bf16)fe[e];
                *(bf16x8*)(hb + jg * 128) = h;
            }
        }
    }

    // epilogue: C/D layout col = lane&15, row = (lane>>4)*4 + reg
    int rbase = ti * 64 + wr * 32 + ((lane >> 4) << 2);
    int cbase = tj * 64 + wc * 32 + (lane & 15);
    _Float16* gb = Gp + (size_t)ks * NN * NN;
    f32x4 accs[2][2] = {{acc00, acc01}, {acc10, acc11}};
#pragma unroll
    for (int g = 0; g < 2; g++)
#pragma unroll
        for (int h = 0; h < 2; h++)
#pragma unroll
            for (int rr = 0; rr < 4; rr++)
                gb[(size_t)(rbase + g * 16 + rr) * NN + cbase + h * 16] =
                    (_Float16)accs[g][h][rr];

    // diagonal harvest (fp32): lanes holding row==col in diagonal tiles
    if (ti == tj && wr == wc && ((lane >> 4) == ((lane & 15) >> 2))) {
        int rr = lane & 3;
        int row0 = rbase + rr;
        ndiag[ks * NN + row0]      = acc00[rr];
        ndiag[ks * NN + row0 + 16] = acc11[rr];
    }
}

// ---------------------------------------------------------------------------
// K2: fused hard mining + local DTW loss + finalize.
//     ni from uniform (scalar-broadcast) ndiag loads; no LDS norm stage.
//     LF[i] prefetched at kernel start (no dependency on mining).
// ---------------------------------------------------------------------------
__global__ __launch_bounds__(256) void k_mine_local(
    const _Float16* __restrict__ Gp, const float* __restrict__ ndiag,
    const int* __restrict__ tg, const float* __restrict__ LF,
    float* gsum, float* lsum, unsigned* counter, float* __restrict__ out)
{
    __shared__ float s_apv[4]; __shared__ int s_api[4];
    __shared__ float s_anv[4]; __shared__ int s_ani[4];
    __shared__ int sh_pn[2];
    __shared__ float A2[LDIM * PARTS];
    __shared__ float B2[2][LDIM * PARTS];
    __shared__ float dtm[2][64];
    __shared__ float res[2];

    int i = blockIdx.x;
    int t = threadIdx.x;

    // prefetch lf[i] (independent of mining)
    float4 a2v = ((const float4*)(LF + (size_t)i * LDIM * PARTS))[t];

    float ni = 0.f, d0 = 0.f, d1 = 0.f;
#pragma unroll
    for (int ks = 0; ks < 8; ks++) {
        ni += ndiag[ks * NN + i];          // uniform -> s_load broadcast
        d0 += ndiag[ks * NN + t];
        d1 += ndiag[ks * NN + t + 256];
    }

    int tgt_i = tg[i];

    float apv = -BIGF; int api = 0x7fffffff;
    float anv =  BIGF; int ani = 0x7fffffff;

#pragma unroll
    for (int jj = 0; jj < 2; jj++) {
        int j = t + jj * 256;
        float g = 0.f;
#pragma unroll
        for (int ks = 0; ks < 8; ks++)
            g += (float)Gp[(size_t)ks * NN * NN + (size_t)i * NN + j];
        float nj = (jj == 0) ? d0 : d1;
        float dd = ni + nj - 2.0f * g;
        float dist = sqrtf(fmaxf(dd, 1e-12f));
        bool pos = (tg[j] == tgt_i);
        float a = pos ? dist : -BIGF;
        if (a > apv || (a == apv && j < api)) { apv = a; api = j; }
        float b = pos ? BIGF : dist;
        if (b < anv || (b == anv && j < ani)) { anv = b; ani = j; }
    }
    // wave reduction with first-index tie-break (matches jnp.argmax/argmin)
    for (int off = 32; off > 0; off >>= 1) {
        float av = __shfl_down(apv, off); int ai = __shfl_down(api, off);
        if (av > apv || (av == apv && ai < api)) { apv = av; api = ai; }
        float nv = __shfl_down(anv, off); int nid = __shfl_down(ani, off);
        if (nv < anv || (nv == anv && nid < ani)) { anv = nv; ani = nid; }
    }
    int lane = t & 63, wid = t >> 6;
    if (lane == 0) { s_apv[wid] = apv; s_api[wid] = api;
                     s_anv[wid] = anv; s_ani[wid] = ani; }
    __syncthreads();
    if (t == 0) {
        apv = s_apv[0]; api = s_api[0]; anv = s_anv[0]; ani = s_ani[0];
        for (int wv = 1; wv < 4; wv++) {
            float av = s_apv[wv]; int ai = s_api[wv];
            if (av > apv || (av == apv && ai < api)) { apv = av; api = ai; }
            float nv = s_anv[wv]; int nid = s_ani[wv];
            if (nv < anv || (nv == anv && nid < ani)) { anv = nv; ani = nid; }
        }
        sh_pn[0] = api;
        sh_pn[1] = ani;
        atomicAdd(gsum, fmaxf(0.0f, MARGIN + apv - anv));
    }
    __syncthreads();

    // phase 2: local DTW loss. wave 0 = positive pair, wave 1 = negative pair.
    int w = t >> 6;
    ((float4*)A2)[t] = a2v;
    if (w < 2) {
        int ind = sh_pn[w];
        const float4* B4 = (const float4*)(LF + (size_t)ind * LDIM * PARTS);
        float4* Bw = (float4*)B2[w];
        Bw[lane]       = B4[lane];
        Bw[lane + 64]  = B4[lane + 64];
        Bw[lane + 128] = B4[lane + 128];
        Bw[lane + 192] = B4[lane + 192];
    }
    __syncthreads();

    if (w < 2) {
        int p = lane >> 3, q = lane & 7;
        float acc = 0.0f;
        const float* Bw = B2[w];
        for (int d = 0; d < LDIM; d++) {
            float diff = A2[d * PARTS + p] - Bw[d * PARTS + q];
            acc = fmaf(diff, diff, acc);
        }
        float dist = sqrtf(fmaxf(acc, 1e-12f));
        dtm[w][p * 8 + q] = tanhf(0.5f * dist);
    }
    __syncthreads();

    if ((t == 0) || (t == 64)) {
        const float* dm = dtm[w];
        float dp[8];
        dp[0] = dm[0];
        for (int j = 1; j < 8; j++) dp[j] = dp[j - 1] + dm[j];
        for (int rr = 1; rr < 8; rr++) {
            dp[0] += dm[rr * 8];
            for (int j = 1; j < 8; j++)
                dp[j] = dm[rr * 8 + j] + fminf(dp[j], dp[j - 1]);
        }
        res[w] = dp[7];
    }
    __syncthreads();

    if (t == 0) {
        float l = fmaxf(0.0f, MARGIN + res[0] - res[1]);
        atomicAdd(lsum, l);
        __threadfence();
        unsigned old = atomicAdd(counter, 1u);
        if (old == (NN - 1)) {
            __threadfence();
            float ls = atomicAdd(lsum, 0.0f);
            float gs = atomicAdd(gsum, 0.0f);
            out[0] = gs * (1.0f / NN);
            out[1] = ls * (1.0f / NN);
        }
    }
}

// ---------------------------------------------------------------------------
extern "C" void kernel_launch(void* const* d_in, const int* in_sizes, int n_in,
                              void* d_out, int out_size, void* d_ws, size_t ws_size,
                              hipStream_t stream)
{
    const float* X  = (const float*)d_in[0];   // [512, 2048] fp32
    const int*   tg = (const int*)d_in[1];     // [512] int
    const float* LF = (const float*)d_in[2];   // [512, 128, 8] fp32
    float* out = (float*)d_out;                // 2 fp32 scalars

    char* ws = (char*)d_ws;
    _Float16* Gp      = (_Float16*)ws;                       // 8 x 512 KB fp16 partials
    float*    ndiag   = (float*)(ws + (4u << 20));           // 16 KB
    float*    gsum    = (float*)(ws + (4u << 20) + 16384);
    float*    lsum    = (float*)(ws + (4u << 20) + 16388);
    unsigned* counter = (unsigned*)(ws + (4u << 20) + 16392);

    k_gram<<<512, 256, 0, stream>>>(X, Gp, ndiag, gsum, lsum, counter);
    k_mine_local<<<512, 256, 0, stream>>>(Gp, ndiag, tg, LF, gsum, lsum, counter, out);
}